// Round 4
// baseline (223.178 us; speedup 1.0000x reference)
//
#include <hip/hip_runtime.h>
#include <hip/hip_bf16.h>
#include <stdint.h>

typedef __attribute__((ext_vector_type(8))) short short8;
typedef __attribute__((ext_vector_type(4))) float float4_t;

#define N_PTS 1024
#define G_DIM 620
#define G_PAD 640
#define F_DIM 20
#define H_DIM 150
#define H_PAD 160
#define K_WIN 128
#define OUT_C (K_WIN + 1)

__device__ __forceinline__ float bf2f(short u) {
  union { unsigned int i; float f; } x;
  x.i = ((unsigned int)(unsigned short)u) << 16;
  return x.f;
}
__device__ __forceinline__ short f2bf(float f) {
  union { float f; unsigned int i; } x; x.f = f;
  unsigned int u = x.i;
  u += 0x7FFFu + ((u >> 16) & 1u);   // RNE
  return (short)(u >> 16);
}
__device__ __forceinline__ short f2bf_hw(float f) {
  __hip_bfloat16 h = __float2bfloat16(f);
  union { __hip_bfloat16 h; short s; } u; u.h = h;
  return u.s;
}
__device__ __forceinline__ void gload_lds16(const void* g, void* l) {
  __builtin_amdgcn_global_load_lds(
      (const __attribute__((address_space(1))) unsigned int*)g,
      (__attribute__((address_space(3))) unsigned int*)l, 16, 0, 0);
}

// ---------------------------------------------------------------------------
// prep_all: single fused prep kernel, grid 313 x 256.
//  [0,256)   : g_bf [1024][640] bf16
//  [256,276) : W1cT [160][640] bf16 (transpose via LDS tiles)
//  [276,280) : W2T  [160][160] bf16
//  [280]     : deWT_g [160][64] bf16 (cols 0..8 = (dist_emb@W1d)^T, col 9..63 = 0)
//  [281,313) : uv GEMM blocks (self-converting, independent of pack blocks):
//              y=0 -> U_bf [1024][160] bf16 (+b1) ; y=1 -> V [1024][160] f32
// ---------------------------------------------------------------------------
__global__ void prep_all(const float* __restrict__ g, const float* __restrict__ W1,
                         const float* __restrict__ W2, const float* __restrict__ dist_emb,
                         const float* __restrict__ b1,
                         short* __restrict__ g_bf, short* __restrict__ W1cT,
                         short* __restrict__ W2T, short* __restrict__ deWT_g,
                         short* __restrict__ U_bf, float* __restrict__ V) {
  __shared__ __align__(16) char psm[32256];
  const int bx = blockIdx.x, tid = threadIdx.x;

  if (bx < 256) {                       // ---- g_bf ----
    const int n0 = bx * 4;
    for (int c = tid; c < 320; c += 256) {
      int r = c / 80, cc = c - r * 80;
      int n = n0 + r, d0 = cc * 8;
      short8 o;
      if (d0 + 8 <= G_DIM) {
        const float* src = g + n * G_DIM + d0;
        #pragma unroll
        for (int e = 0; e < 8; ++e) o[e] = f2bf(src[e]);
      } else {
        #pragma unroll
        for (int e = 0; e < 8; ++e) {
          int d = d0 + e;
          o[e] = (d < G_DIM) ? f2bf(g[n * G_DIM + d]) : (short)0;
        }
      }
      *(short8*)(g_bf + n * G_PAD + d0) = o;
    }
  } else if (bx < 276) {                // ---- W1cT transpose ----
    float* lds = (float*)psm;           // [32][165]
    const int dt = bx - 256;
    const int d0 = dt * 32;
    for (int c = tid; c < 1280; c += 256) {
      int dr = c / 40, ch4 = c - dr * 40;
      int dd = d0 + dr;
      #pragma unroll
      for (int e = 0; e < 4; ++e) {
        int h = ch4 * 4 + e;
        lds[dr * 165 + h] = (dd < G_DIM && h < H_DIM) ? W1[(2 * G_DIM + dd) * H_DIM + h] : 0.f;
      }
    }
    __syncthreads();
    for (int c = tid; c < 640; c += 256) {
      int h = c >> 2, ch = c & 3;
      short8 o;
      #pragma unroll
      for (int e = 0; e < 8; ++e) o[e] = f2bf(lds[(ch * 8 + e) * 165 + h]);
      *(short8*)(W1cT + h * G_PAD + d0 + ch * 8) = o;
    }
  } else if (bx < 280) {                // ---- W2T ----
    const int base = (bx - 276) * 6400;
    for (int c = tid; c < 6400; c += 256) {
      int q = base + c;
      int m = q / H_PAD, k = q - m * H_PAD;
      W2T[q] = (m < H_DIM && k < H_DIM) ? f2bf(W2[k * H_DIM + m]) : (short)0;
    }
  } else if (bx == 280) {               // ---- deWT_g ----
    float* dw = (float*)psm;            // [9][160]
    for (int c = tid; c < 9 * H_PAD; c += 256) {
      int b = c / H_PAD, h = c - b * H_PAD;
      float acc = 0.f;
      if (h < H_DIM)
        for (int f = 0; f < F_DIM; ++f)
          acc += dist_emb[b * F_DIM + f] * W1[(3 * G_DIM + f) * H_DIM + h];
      dw[c] = acc;
    }
    __syncthreads();
    for (int c = tid; c < H_PAD * 8; c += 256) {
      int row = c >> 3, ch = c & 7;
      short8 o;
      #pragma unroll
      for (int e = 0; e < 8; ++e) {
        int kk = ch * 8 + e;
        o[e] = (kk < 9) ? f2bf(dw[kk * H_PAD + row]) : (short)0;
      }
      *(short8*)(deWT_g + row * 64 + ch * 8) = o;
    }
  } else {                              // ---- uv GEMM (self-converting) ----
    char* AsB = psm;                    // [64][144B]  A tile bf16
    char* WtT = psm + 64 * 144;         // [160][144B] B tile bf16 (transposed)
    const int uvb = bx - 281;
    const int y = uvb >> 4;             // 0 = U, 1 = V
    const int m0 = (uvb & 15) * 64;
    const int lane = tid & 63, wid = tid >> 6;
    const int wm = wid >> 1, wn = wid & 1;
    const int lo4 = lane & 15, hi2 = lane >> 4;
    const float* W1y = W1 + y * G_DIM * H_DIM;

    const float4_t fz = {0.f, 0.f, 0.f, 0.f};
    float4_t acc[2][5];
    #pragma unroll
    for (int a = 0; a < 2; ++a)
      #pragma unroll
      for (int b = 0; b < 5; ++b) acc[a][b] = fz;

    for (int step = 0; step < 10; ++step) {
      const int d0 = step * 64;
      __syncthreads();
      {  // stage A: rows m0..m0+63, cols d0..d0+63 (f32 -> bf16)
        int r = tid >> 2, q = tid & 3;
        const float* gr = g + (m0 + r) * G_DIM;
        short8 o0, o1;
        #pragma unroll
        for (int e = 0; e < 8; ++e) {
          int d = d0 + q * 16 + e;
          o0[e] = (d < G_DIM) ? f2bf(gr[d]) : (short)0;
          int d2 = d + 8;
          o1[e] = (d2 < G_DIM) ? f2bf(gr[d2]) : (short)0;
        }
        *(short8*)(AsB + r * 144 + q * 32) = o0;
        *(short8*)(AsB + r * 144 + q * 32 + 16) = o1;
      }
      // stage B transposed: WtT[h][dr] = W1y[d0+dr][h]
      for (int c = tid; c < 64 * 160; c += 256) {
        int dr = c / 160, h = c - dr * 160;
        int d = d0 + dr;
        float w = (h < H_DIM && d < G_DIM) ? W1y[d * H_DIM + h] : 0.f;
        *(short*)(WtT + h * 144 + dr * 2) = f2bf(w);
      }
      __syncthreads();
      #pragma unroll
      for (int ks = 0; ks < 2; ++ks) {
        const int kb = ks * 64 + hi2 * 16;
        short8 af[2], bq[5];
        #pragma unroll
        for (int mt = 0; mt < 2; ++mt) {
          int row = wm * 32 + mt * 16 + lo4;
          af[mt] = *((const short8*)(AsB + row * 144 + kb));
        }
        #pragma unroll
        for (int nt = 0; nt < 5; ++nt) {
          int row = wn * 80 + nt * 16 + lo4;
          bq[nt] = *((const short8*)(WtT + row * 144 + kb));
        }
        #pragma unroll
        for (int mt = 0; mt < 2; ++mt)
          #pragma unroll
          for (int nt = 0; nt < 5; ++nt)
            acc[mt][nt] = __builtin_amdgcn_mfma_f32_16x16x32_bf16(af[mt], bq[nt], acc[mt][nt], 0, 0, 0);
      }
    }
    #pragma unroll
    for (int mt = 0; mt < 2; ++mt)
      #pragma unroll
      for (int r = 0; r < 4; ++r) {
        int m = m0 + wm * 32 + mt * 16 + hi2 * 4 + r;
        #pragma unroll
        for (int nt = 0; nt < 5; ++nt) {
          int h = wn * 80 + nt * 16 + lo4;
          float v = acc[mt][nt][r];
          if (y == 0) {
            v = (h < H_DIM) ? v + b1[h] : 0.f;
            U_bf[m * H_PAD + h] = f2bf(v);
          } else {
            V[m * H_PAD + h] = (h < H_DIM) ? v : 0.f;
          }
        }
      }
  }
}

// ---------------------------------------------------------------------------
// pair_main: one block per i (XCD swizzle). 4 waves (2M x 2N), 3 blocks/CU.
// Layer1: A-fragments (g_i .* g_j) built IN REGISTERS (no P LDS tile);
//         B = W1cT staged via global_load_lds, 128B XOR rows, dbuf, BK=64.
//         10 data iters + 1 aug iter (folds U+b1+deW[bin]), 1 barrier/iter.
// Layer2: h1(LDS, swizzled) @ W2T(direct global, reg dbuf).
// ---------------------------------------------------------------------------
__global__ __launch_bounds__(256, 3) void pair_main(
    const float* __restrict__ g, const short* __restrict__ g_bf,
    const short* __restrict__ W1cT, const short* __restrict__ W2T,
    const short* __restrict__ U_bf, const float* __restrict__ V,
    const short* __restrict__ deWT_g, const float* __restrict__ si,
    const int* __restrict__ i1, const int* __restrict__ i2,
    const float* __restrict__ W3, const float* __restrict__ b2,
    const float* __restrict__ b3, float* __restrict__ out) {
  __shared__ __align__(16) char smem[49152];     // B0|B1 (2x20480) / Hb (3x16384)
  __shared__ __align__(16) float gi_sf[G_PAD];
  __shared__ float sj_s[K_WIN];
  __shared__ unsigned char bin_su[K_WIN];
  __shared__ float s_buf[2][K_WIN];

  char* const B0 = smem;
  char* const B1 = smem + 20480;
  char* const Hb = smem;

  const int bid = blockIdx.x;
  const int i = ((bid & 7) << 7) | (bid >> 3);   // XCD-bijective swizzle
  const int tid = threadIdx.x;
  const int lane = tid & 63;
  const int wid = tid >> 6;
  const int wm = wid >> 1, wn = wid & 1;
  const int lo4 = lane & 15, hi2 = lane >> 4;
  const int l8 = lane >> 3, c8 = lane & 7;
  const int xe = (c8 ^ (l8 & 7)) * 8;            // pre-swizzled source chunk

  // ---- preamble ----
  if (tid < 160) {
    int c = tid;
    float4_t v;
    if (c < 155) v = *(const float4_t*)(g + i * G_DIM + c * 4);
    else { v.x = v.y = v.z = v.w = 0.f; }
    *(float4_t*)(gi_sf + c * 4) = v;
  }
  if (tid < K_WIN) {
    int jr = i - K_WIN + tid, jc = jr < 0 ? 0 : jr;
    int d = i2[i] - i1[jc];
    bin_su[tid] = (unsigned char)((d >= 1) + (d >= 2) + (d >= 3) + (d >= 4) +
                                  (d >= 8) + (d >= 16) + (d >= 32) + (d >= 64));
    sj_s[tid] = si[jc];
  }
  __syncthreads();

  // per-lane A-row source pointers + aug one-hot indices
  const short* gA[4];
  int bv[4];
  #pragma unroll
  for (int mt = 0; mt < 4; ++mt) {
    int row = wm * 64 + mt * 16 + lo4;
    int jr = i - K_WIN + row, jc = jr < 0 ? 0 : jr;
    gA[mt] = g_bf + jc * G_PAD + hi2 * 8;
    bv[mt] = bin_su[row];
  }

  auto stageB = [&](const short* src, int sstride, char* B) {
    #pragma unroll
    for (int cc = 0; cc < 5; ++cc) {
      int row = wid * 8 + cc * 32 + l8;
      gload_lds16(src + row * sstride + xe, B + (wid * 8 + cc * 32) * 128);
    }
  };

  const float4_t fz = {0.f, 0.f, 0.f, 0.f};
  float4_t acc[4][5];
  #pragma unroll
  for (int a = 0; a < 4; ++a)
    #pragma unroll
    for (int b = 0; b < 5; ++b) acc[a][b] = fz;

  stageB(W1cT, G_PAD, B0);               // prologue: stage step 0

  // ---- layer 1: 10 data iters, 1 barrier each ----
  for (int s = 0; s < 10; ++s) {
    char* Bc = (s & 1) ? B1 : B0;
    char* Bn = (s & 1) ? B0 : B1;
    __syncthreads();                     // cur staged (vmcnt(0) drained by syncthreads)
    // gj chunk loads for this step (L2-resident; TLP hides latency)
    short8 gj[4][2];
    #pragma unroll
    for (int mt = 0; mt < 4; ++mt)
      #pragma unroll
      for (int ks = 0; ks < 2; ++ks)
        gj[mt][ks] = *(const short8*)(gA[mt] + s * 64 + ks * 32);
    // stage next (async, in flight across MFMA)
    if (s < 9) stageB(W1cT + (s + 1) * 64, G_PAD, Bn);
    else       stageB(deWT_g, 64, Bn);   // aug tile
    #pragma unroll
    for (int ks = 0; ks < 2; ++ks) {
      // g_i slice (LDS broadcast) + in-register product fragments
      const float* gis = gi_sf + s * 64 + ks * 32 + hi2 * 8;
      float4_t g0 = *(const float4_t*)(gis);
      float4_t g1 = *(const float4_t*)(gis + 4);
      short8 af[4];
      #pragma unroll
      for (int mt = 0; mt < 4; ++mt) {
        #pragma unroll
        for (int e = 0; e < 4; ++e) {
          af[mt][e]     = f2bf_hw(bf2f(gj[mt][ks][e])     * g0[e]);
          af[mt][e + 4] = f2bf_hw(bf2f(gj[mt][ks][e + 4]) * g1[e]);
        }
      }
      const int kb = ks * 64 + hi2 * 16;
      short8 bq[5];
      #pragma unroll
      for (int nt = 0; nt < 5; ++nt) {
        int row = wn * 80 + nt * 16 + lo4;
        bq[nt] = *((const short8*)(Bc + row * 128 + (kb ^ ((row & 7) << 4))));
      }
      #pragma unroll
      for (int mt = 0; mt < 4; ++mt)
        #pragma unroll
        for (int nt = 0; nt < 5; ++nt)
          acc[mt][nt] = __builtin_amdgcn_mfma_f32_16x16x32_bf16(af[mt], bq[nt], acc[mt][nt], 0, 0, 0);
    }
  }

  // ---- aug iter: A = one-hot(bin) + k==9, B = deWT_g with U col inserted ----
  {
    char* Bc = B0;                       // 10 & 1 == 0
    __syncthreads();                     // aug tile staged
    if (tid < H_PAD) {
      int row = tid;
      *(short*)(Bc + row * 128 + (18 ^ ((row & 7) << 4))) = U_bf[i * H_PAD + row];
    }
    __syncthreads();
    #pragma unroll
    for (int ks = 0; ks < 2; ++ks) {
      short8 af[4];
      #pragma unroll
      for (int mt = 0; mt < 4; ++mt) {
        #pragma unroll
        for (int e = 0; e < 8; ++e) {
          int k = ks * 32 + hi2 * 8 + e;
          af[mt][e] = (k == bv[mt] || k == 9) ? (short)0x3F80 : (short)0;
        }
      }
      const int kb = ks * 64 + hi2 * 16;
      short8 bq[5];
      #pragma unroll
      for (int nt = 0; nt < 5; ++nt) {
        int row = wn * 80 + nt * 16 + lo4;
        bq[nt] = *((const short8*)(Bc + row * 128 + (kb ^ ((row & 7) << 4))));
      }
      #pragma unroll
      for (int mt = 0; mt < 4; ++mt)
        #pragma unroll
        for (int nt = 0; nt < 5; ++nt)
          acc[mt][nt] = __builtin_amdgcn_mfma_f32_16x16x32_bf16(af[mt], bq[nt], acc[mt][nt], 0, 0, 0);
    }
  }
  __syncthreads();   // layer-1 B reads done; Hb may overwrite B0/B1

  // ---- epilogue 1: h1 = relu(acc + V[j]) -> Hb bf16 swizzled tiles ----
  #pragma unroll
  for (int mt = 0; mt < 4; ++mt) {
    #pragma unroll
    for (int r = 0; r < 4; ++r) {
      int m = wm * 64 + mt * 16 + hi2 * 4 + r;
      int jr = i - K_WIN + m, jc = jr < 0 ? 0 : jr;
      const float* Vj = V + jc * H_PAD;
      #pragma unroll
      for (int nt = 0; nt < 5; ++nt) {
        int h = wn * 80 + nt * 16 + lo4;
        float val = acc[mt][nt][r] + Vj[h];
        val = (h < H_DIM) ? fmaxf(val, 0.f) : 0.f;
        int tile = h >> 6, hc = h & 63;
        int byte = tile * 16384 + m * 128 + ((hc * 2) ^ ((m & 7) << 4));
        *((short*)(Hb + byte)) = f2bf_hw(val);
      }
    }
  }
  // zero tile2 bytes 64..127 (XOR addressing touches them for k=128..159 reads)
  {
    short8 z = {0, 0, 0, 0, 0, 0, 0, 0};
    for (int c = tid; c < 512; c += 256) {
      int row = c >> 2, cb = c & 3;
      int byte = 2 * 16384 + row * 128 + ((64 + cb * 16) ^ ((row & 7) << 4));
      *((short8*)(Hb + byte)) = z;
    }
  }
  __syncthreads();

  // ---- layer 2: D2 = h1 @ W2 (K=160), B direct from global (L2), reg dbuf ----
  float4_t acc2[4][5];
  #pragma unroll
  for (int a = 0; a < 4; ++a)
    #pragma unroll
    for (int b = 0; b < 5; ++b) acc2[a][b] = fz;

  short8 bql[2][5];
  #pragma unroll
  for (int nt = 0; nt < 5; ++nt) {
    int row = wn * 80 + nt * 16 + lo4;
    bql[0][nt] = *(const short8*)(W2T + row * H_PAD + hi2 * 8);
  }
  #pragma unroll
  for (int ks = 0; ks < 5; ++ks) {
    const int cur = ks & 1;
    if (ks < 4) {
      #pragma unroll
      for (int nt = 0; nt < 5; ++nt) {
        int row = wn * 80 + nt * 16 + lo4;
        bql[cur ^ 1][nt] = *(const short8*)(W2T + row * H_PAD + (ks + 1) * 32 + hi2 * 8);
      }
    }
    short8 af[4];
    #pragma unroll
    for (int mt = 0; mt < 4; ++mt) {
      int row = wm * 64 + mt * 16 + lo4;
      int kb = (ks & 1) * 64 + hi2 * 16;
      af[mt] = *((const short8*)(Hb + (ks >> 1) * 16384 + row * 128 + (kb ^ ((row & 7) << 4))));
    }
    #pragma unroll
    for (int mt = 0; mt < 4; ++mt)
      #pragma unroll
      for (int nt = 0; nt < 5; ++nt)
        acc2[mt][nt] = __builtin_amdgcn_mfma_f32_16x16x32_bf16(af[mt], bql[cur][nt], acc2[mt][nt], 0, 0, 0);
  }

  // ---- epilogue 2: s = relu(acc2 + b2) @ W3, reduce, emit ----
  float sp[4][4];
  #pragma unroll
  for (int mt = 0; mt < 4; ++mt)
    #pragma unroll
    for (int r = 0; r < 4; ++r) sp[mt][r] = 0.f;

  #pragma unroll
  for (int nt = 0; nt < 5; ++nt) {
    int h = wn * 80 + nt * 16 + lo4;
    float w3 = (h < H_DIM) ? W3[h] : 0.f;
    float bb = (h < H_DIM) ? b2[h] : 0.f;
    #pragma unroll
    for (int mt = 0; mt < 4; ++mt)
      #pragma unroll
      for (int r = 0; r < 4; ++r) {
        float hv = fmaxf(acc2[mt][nt][r] + bb, 0.f);
        sp[mt][r] += hv * w3;
      }
  }
  #pragma unroll
  for (int mt = 0; mt < 4; ++mt)
    #pragma unroll
    for (int r = 0; r < 4; ++r) {
      float v = sp[mt][r];
      v += __shfl_xor(v, 1);
      v += __shfl_xor(v, 2);
      v += __shfl_xor(v, 4);
      v += __shfl_xor(v, 8);
      sp[mt][r] = v;
    }
  if (lo4 == 0) {
    #pragma unroll
    for (int mt = 0; mt < 4; ++mt)
      #pragma unroll
      for (int r = 0; r < 4; ++r) {
        int m = wm * 64 + mt * 16 + hi2 * 4 + r;
        s_buf[wn][m] = sp[mt][r];
      }
  }
  __syncthreads();

  if (tid < K_WIN) {
    int m = tid;
    int jr = i - K_WIN + m;
    float sij = si[i] + sj_s[m] + s_buf[0][m] + s_buf[1][m] + b3[0];
    out[i * OUT_C + m] = (jr >= 0) ? sij : 0.f;
  }
  if (tid == K_WIN) out[i * OUT_C + K_WIN] = 0.f;
}

// ---------------------------------------------------------------------------
extern "C" void kernel_launch(void* const* d_in, const int* in_sizes, int n_in,
                              void* d_out, int out_size, void* d_ws, size_t ws_size,
                              hipStream_t stream) {
  const float* g  = (const float*)d_in[0];
  const float* si = (const float*)d_in[1];
  const int*   i1 = (const int*)d_in[2];
  const int*   i2 = (const int*)d_in[3];
  const float* de = (const float*)d_in[4];
  const float* W1 = (const float*)d_in[5];
  const float* b1 = (const float*)d_in[6];
  const float* W2 = (const float*)d_in[7];
  const float* b2 = (const float*)d_in[8];
  const float* W3 = (const float*)d_in[9];
  const float* b3 = (const float*)d_in[10];
  float* out = (float*)d_out;

  char* ws = (char*)d_ws;
  short* g_bf   = (short*)(ws);                 // 1,310,720
  short* W1cT   = (short*)(ws + 1310720);       //   204,800
  short* W2T    = (short*)(ws + 1515520);       //    51,200
  short* deWT_g = (short*)(ws + 1566720);       //    20,480
  float* V      = (float*)(ws + 1587200);       //   655,360
  short* U_bf   = (short*)(ws + 2242560);       //   327,680  (total ~2.57 MB)

  prep_all<<<313, 256, 0, stream>>>(g, W1, W2, de, b1, g_bf, W1cT, W2T, deWT_g, U_bf, V);
  pair_main<<<N_PTS, 256, 0, stream>>>(g, g_bf, W1cT, W2T, U_bf, V, deWT_g,
                                       si, i1, i2, W3, b2, b3, out);
}

// Round 5
// 108.800 us; speedup vs baseline: 2.0513x; 2.0513x over previous
//
#include <hip/hip_runtime.h>
#include <hip/hip_bf16.h>
#include <stdint.h>

typedef __attribute__((ext_vector_type(8))) short short8;
typedef __attribute__((ext_vector_type(4))) float float4_t;

#define N_PTS 1024
#define G_DIM 620
#define G_PAD 640
#define F_DIM 20
#define H_DIM 150
#define H_PAD 160
#define K_WIN 128
#define OUT_C (K_WIN + 1)

__device__ __forceinline__ float bf2f(short u) {
  union { unsigned int i; float f; } x;
  x.i = ((unsigned int)(unsigned short)u) << 16;
  return x.f;
}
__device__ __forceinline__ short f2bf(float f) {
  union { float f; unsigned int i; } x; x.f = f;
  unsigned int u = x.i;
  u += 0x7FFFu + ((u >> 16) & 1u);   // RNE
  return (short)(u >> 16);
}
__device__ __forceinline__ short f2bf_hw(float f) {
  __hip_bfloat16 h = __float2bfloat16(f);
  union { __hip_bfloat16 h; short s; } u; u.h = h;
  return u.s;
}
__device__ __forceinline__ void gload_lds16(const void* g, void* l) {
  __builtin_amdgcn_global_load_lds(
      (const __attribute__((address_space(1))) unsigned int*)g,
      (__attribute__((address_space(3))) unsigned int*)l, 16, 0, 0);
}

// ---------------------------------------------------------------------------
// prep_pack: grid 321 x 256 (r3 structure — measured fast).
//  [0,256)   : g_bf [1024][640] bf16 (4 rows/block, vectorized)
//  [256,316) : LDS-tiled transposes (32-d x 160-h tiles):
//              third 0 -> W1abT rows 0..159   (W1a^T)
//              third 1 -> W1abT rows 160..319 (W1b^T)
//              third 2 -> W1cT  [160][640]
//  [316,320) : W2T [160][160]
//  [320]     : deWT_g [160][64] bf16 (cols 0..8 = (dist_emb@W1d)^T, 9..63 = 0)
// ---------------------------------------------------------------------------
__global__ void prep_pack(const float* __restrict__ g, const float* __restrict__ W1,
                          const float* __restrict__ W2, const float* __restrict__ dist_emb,
                          short* __restrict__ g_bf, short* __restrict__ W1cT,
                          short* __restrict__ W1abT, short* __restrict__ W2T,
                          short* __restrict__ deWT_g) {
  __shared__ float lds[32 * 165];
  __shared__ float dw[9 * H_PAD];
  const int bx = blockIdx.x, tid = threadIdx.x;
  if (bx < 256) {
    const int n0 = bx * 4;
    for (int c = tid; c < 320; c += 256) {
      int r = c / 80, cc = c - r * 80;
      int n = n0 + r, d0 = cc * 8;
      short8 o;
      if (d0 + 8 <= G_DIM) {
        const float* src = g + n * G_DIM + d0;
        #pragma unroll
        for (int e = 0; e < 8; ++e) o[e] = f2bf(src[e]);
      } else {
        #pragma unroll
        for (int e = 0; e < 8; ++e) {
          int d = d0 + e;
          o[e] = (d < G_DIM) ? f2bf(g[n * G_DIM + d]) : (short)0;
        }
      }
      *(short8*)(g_bf + n * G_PAD + d0) = o;
    }
  } else if (bx < 316) {
    const int tb = bx - 256;
    const int third = tb / 20, dt = tb - third * 20;
    const int d0 = dt * 32;
    for (int c = tid; c < 1280; c += 256) {       // 32 d-rows x 40 chunks(4h)
      int dr = c / 40, ch4 = c - dr * 40;
      int dd = d0 + dr;
      int w1r = third * G_DIM + dd;
      #pragma unroll
      for (int e = 0; e < 4; ++e) {
        int h = ch4 * 4 + e;
        lds[dr * 165 + h] = (dd < G_DIM && h < H_DIM) ? W1[w1r * H_DIM + h] : 0.f;
      }
    }
    __syncthreads();
    short* outp = (third == 2) ? W1cT : (W1abT + third * H_PAD * G_PAD);
    for (int c = tid; c < 640; c += 256) {        // 160 h-rows x 4 chunks(8d)
      int h = c >> 2, ch = c & 3;
      short8 o;
      #pragma unroll
      for (int e = 0; e < 8; ++e) o[e] = f2bf(lds[(ch * 8 + e) * 165 + h]);
      *(short8*)(outp + h * G_PAD + d0 + ch * 8) = o;
    }
  } else if (bx < 320) {
    const int base = (bx - 316) * 6400;
    for (int c = tid; c < 6400; c += 256) {
      int q = base + c;
      int m = q / H_PAD, k = q - m * H_PAD;
      W2T[q] = (m < H_DIM && k < H_DIM) ? f2bf(W2[k * H_DIM + m]) : (short)0;
    }
  } else {
    for (int c = tid; c < 9 * H_PAD; c += 256) {
      int b = c / H_PAD, h = c - b * H_PAD;
      float acc = 0.f;
      if (h < H_DIM)
        for (int f = 0; f < F_DIM; ++f)
          acc += dist_emb[b * F_DIM + f] * W1[(3 * G_DIM + f) * H_DIM + h];
      dw[c] = acc;
    }
    __syncthreads();
    for (int c = tid; c < H_PAD * 8; c += 256) {
      int row = c >> 3, ch = c & 7;
      short8 o;
      #pragma unroll
      for (int e = 0; e < 8; ++e) {
        int kk = ch * 8 + e;
        o[e] = (kk < 9) ? f2bf(dw[kk * H_PAD + row]) : (short)0;
      }
      *(short8*)(deWT_g + row * 64 + ch * 8) = o;
    }
  }
}

// ---------------------------------------------------------------------------
// prep_uv_mfma: y=0 -> U_bf (bf16, +b1) ; y=1 -> V (f32). 64 rows/block.
// Consumes pre-converted g_bf / W1abT via global_load_lds (r3 structure).
// ---------------------------------------------------------------------------
__global__ __launch_bounds__(256) void prep_uv_mfma(
    const short* __restrict__ g_bf, const short* __restrict__ W1abT,
    const float* __restrict__ b1, short* __restrict__ U_bf, float* __restrict__ V) {
  __shared__ __align__(16) char sA[64 * 128];
  __shared__ __align__(16) char sB[160 * 128];
  const int m0 = blockIdx.x * 64;
  const int yb = blockIdx.y * H_PAD;
  const int tid = threadIdx.x, lane = tid & 63, wid = tid >> 6;
  const int wm = wid >> 1, wn = wid & 1;
  const int lo4 = lane & 15, hi2 = lane >> 4;
  const int l8 = lane >> 3, c8 = lane & 7;
  const int xe = (c8 ^ (l8 & 7)) * 8;

  const float4_t fz = {0.f, 0.f, 0.f, 0.f};
  float4_t acc[2][5];
  #pragma unroll
  for (int a = 0; a < 2; ++a)
    #pragma unroll
    for (int b = 0; b < 5; ++b) acc[a][b] = fz;

  for (int step = 0; step < 10; ++step) {
    const int d0 = step * 64;
    #pragma unroll
    for (int cc = 0; cc < 2; ++cc) {
      int row = wid * 8 + cc * 32 + l8;
      gload_lds16(g_bf + (m0 + row) * G_PAD + d0 + xe, sA + (wid * 8 + cc * 32) * 128);
    }
    #pragma unroll
    for (int cc = 0; cc < 5; ++cc) {
      int row = wid * 8 + cc * 32 + l8;
      gload_lds16(W1abT + (yb + row) * G_PAD + d0 + xe, sB + (wid * 8 + cc * 32) * 128);
    }
    __syncthreads();
    #pragma unroll
    for (int ks = 0; ks < 2; ++ks) {
      const int kb = ks * 64 + 16 * hi2;
      short8 af[2], bq[5];
      #pragma unroll
      for (int mt = 0; mt < 2; ++mt) {
        int row = wm * 32 + mt * 16 + lo4;
        af[mt] = *((const short8*)(sA + row * 128 + (kb ^ ((row & 7) << 4))));
      }
      #pragma unroll
      for (int nt = 0; nt < 5; ++nt) {
        int row = wn * 80 + nt * 16 + lo4;
        bq[nt] = *((const short8*)(sB + row * 128 + (kb ^ ((row & 7) << 4))));
      }
      #pragma unroll
      for (int mt = 0; mt < 2; ++mt)
        #pragma unroll
        for (int nt = 0; nt < 5; ++nt)
          acc[mt][nt] = __builtin_amdgcn_mfma_f32_16x16x32_bf16(af[mt], bq[nt], acc[mt][nt], 0, 0, 0);
    }
    __syncthreads();
  }

  const bool isU = (blockIdx.y == 0);
  #pragma unroll
  for (int mt = 0; mt < 2; ++mt)
    #pragma unroll
    for (int r = 0; r < 4; ++r) {
      int m = m0 + wm * 32 + mt * 16 + hi2 * 4 + r;
      #pragma unroll
      for (int nt = 0; nt < 5; ++nt) {
        int h = wn * 80 + nt * 16 + lo4;
        float v = acc[mt][nt][r];
        if (isU) {
          v = (h < H_DIM) ? v + b1[h] : 0.f;
          U_bf[m * H_PAD + h] = f2bf(v);
        } else {
          V[m * H_PAD + h] = (h < H_DIM) ? v : 0.f;
        }
      }
    }
}

// ---------------------------------------------------------------------------
// pair_main: one block per i (XCD swizzle). 4 waves (2M x 2N), 3 blocks/CU.
// Layer1: A-fragments (g_i .* g_j) built IN REGISTERS (no P LDS tile);
//         B = W1cT staged via global_load_lds, 128B XOR rows, dbuf, BK=64.
//         10 data iters + 1 aug iter (folds U+b1+deW[bin]), 1 barrier/iter.
// Layer2: h1(LDS, swizzled) @ W2T(direct global, reg dbuf).
// (unchanged from r4 — passed, and was ~25 us there)
// ---------------------------------------------------------------------------
__global__ __launch_bounds__(256, 3) void pair_main(
    const float* __restrict__ g, const short* __restrict__ g_bf,
    const short* __restrict__ W1cT, const short* __restrict__ W2T,
    const short* __restrict__ U_bf, const float* __restrict__ V,
    const short* __restrict__ deWT_g, const float* __restrict__ si,
    const int* __restrict__ i1, const int* __restrict__ i2,
    const float* __restrict__ W3, const float* __restrict__ b2,
    const float* __restrict__ b3, float* __restrict__ out) {
  __shared__ __align__(16) char smem[49152];     // B0|B1 (2x20480) / Hb (3x16384)
  __shared__ __align__(16) float gi_sf[G_PAD];
  __shared__ float sj_s[K_WIN];
  __shared__ unsigned char bin_su[K_WIN];
  __shared__ float s_buf[2][K_WIN];

  char* const B0 = smem;
  char* const B1 = smem + 20480;
  char* const Hb = smem;

  const int bid = blockIdx.x;
  const int i = ((bid & 7) << 7) | (bid >> 3);   // XCD-bijective swizzle
  const int tid = threadIdx.x;
  const int lane = tid & 63;
  const int wid = tid >> 6;
  const int wm = wid >> 1, wn = wid & 1;
  const int lo4 = lane & 15, hi2 = lane >> 4;
  const int l8 = lane >> 3, c8 = lane & 7;
  const int xe = (c8 ^ (l8 & 7)) * 8;            // pre-swizzled source chunk

  // ---- preamble ----
  if (tid < 160) {
    int c = tid;
    float4_t v;
    if (c < 155) v = *(const float4_t*)(g + i * G_DIM + c * 4);
    else { v.x = v.y = v.z = v.w = 0.f; }
    *(float4_t*)(gi_sf + c * 4) = v;
  }
  if (tid < K_WIN) {
    int jr = i - K_WIN + tid, jc = jr < 0 ? 0 : jr;
    int d = i2[i] - i1[jc];
    bin_su[tid] = (unsigned char)((d >= 1) + (d >= 2) + (d >= 3) + (d >= 4) +
                                  (d >= 8) + (d >= 16) + (d >= 32) + (d >= 64));
    sj_s[tid] = si[jc];
  }
  __syncthreads();

  // per-lane A-row source pointers + aug one-hot indices
  const short* gA[4];
  int bv[4];
  #pragma unroll
  for (int mt = 0; mt < 4; ++mt) {
    int row = wm * 64 + mt * 16 + lo4;
    int jr = i - K_WIN + row, jc = jr < 0 ? 0 : jr;
    gA[mt] = g_bf + jc * G_PAD + hi2 * 8;
    bv[mt] = bin_su[row];
  }

  auto stageB = [&](const short* src, int sstride, char* B) {
    #pragma unroll
    for (int cc = 0; cc < 5; ++cc) {
      int row = wid * 8 + cc * 32 + l8;
      gload_lds16(src + row * sstride + xe, B + (wid * 8 + cc * 32) * 128);
    }
  };

  const float4_t fz = {0.f, 0.f, 0.f, 0.f};
  float4_t acc[4][5];
  #pragma unroll
  for (int a = 0; a < 4; ++a)
    #pragma unroll
    for (int b = 0; b < 5; ++b) acc[a][b] = fz;

  stageB(W1cT, G_PAD, B0);               // prologue: stage step 0

  // ---- layer 1: 10 data iters, 1 barrier each ----
  for (int s = 0; s < 10; ++s) {
    char* Bc = (s & 1) ? B1 : B0;
    char* Bn = (s & 1) ? B0 : B1;
    __syncthreads();                     // cur staged
    short8 gj[4][2];
    #pragma unroll
    for (int mt = 0; mt < 4; ++mt)
      #pragma unroll
      for (int ks = 0; ks < 2; ++ks)
        gj[mt][ks] = *(const short8*)(gA[mt] + s * 64 + ks * 32);
    if (s < 9) stageB(W1cT + (s + 1) * 64, G_PAD, Bn);
    else       stageB(deWT_g, 64, Bn);   // aug tile
    #pragma unroll
    for (int ks = 0; ks < 2; ++ks) {
      const float* gis = gi_sf + s * 64 + ks * 32 + hi2 * 8;
      float4_t g0 = *(const float4_t*)(gis);
      float4_t g1 = *(const float4_t*)(gis + 4);
      short8 af[4];
      #pragma unroll
      for (int mt = 0; mt < 4; ++mt) {
        #pragma unroll
        for (int e = 0; e < 4; ++e) {
          af[mt][e]     = f2bf_hw(bf2f(gj[mt][ks][e])     * g0[e]);
          af[mt][e + 4] = f2bf_hw(bf2f(gj[mt][ks][e + 4]) * g1[e]);
        }
      }
      const int kb = ks * 64 + hi2 * 16;
      short8 bq[5];
      #pragma unroll
      for (int nt = 0; nt < 5; ++nt) {
        int row = wn * 80 + nt * 16 + lo4;
        bq[nt] = *((const short8*)(Bc + row * 128 + (kb ^ ((row & 7) << 4))));
      }
      #pragma unroll
      for (int mt = 0; mt < 4; ++mt)
        #pragma unroll
        for (int nt = 0; nt < 5; ++nt)
          acc[mt][nt] = __builtin_amdgcn_mfma_f32_16x16x32_bf16(af[mt], bq[nt], acc[mt][nt], 0, 0, 0);
    }
  }

  // ---- aug iter: A = one-hot(bin) + k==9, B = deWT_g with U col inserted ----
  {
    char* Bc = B0;                       // 10 & 1 == 0
    __syncthreads();                     // aug tile staged
    if (tid < H_PAD) {
      int row = tid;
      *(short*)(Bc + row * 128 + (18 ^ ((row & 7) << 4))) = U_bf[i * H_PAD + row];
    }
    __syncthreads();
    #pragma unroll
    for (int ks = 0; ks < 2; ++ks) {
      short8 af[4];
      #pragma unroll
      for (int mt = 0; mt < 4; ++mt) {
        #pragma unroll
        for (int e = 0; e < 8; ++e) {
          int k = ks * 32 + hi2 * 8 + e;
          af[mt][e] = (k == bv[mt] || k == 9) ? (short)0x3F80 : (short)0;
        }
      }
      const int kb = ks * 64 + hi2 * 16;
      short8 bq[5];
      #pragma unroll
      for (int nt = 0; nt < 5; ++nt) {
        int row = wn * 80 + nt * 16 + lo4;
        bq[nt] = *((const short8*)(Bc + row * 128 + (kb ^ ((row & 7) << 4))));
      }
      #pragma unroll
      for (int mt = 0; mt < 4; ++mt)
        #pragma unroll
        for (int nt = 0; nt < 5; ++nt)
          acc[mt][nt] = __builtin_amdgcn_mfma_f32_16x16x32_bf16(af[mt], bq[nt], acc[mt][nt], 0, 0, 0);
    }
  }
  __syncthreads();   // layer-1 B reads done; Hb may overwrite B0/B1

  // ---- epilogue 1: h1 = relu(acc + V[j]) -> Hb bf16 swizzled tiles ----
  #pragma unroll
  for (int mt = 0; mt < 4; ++mt) {
    #pragma unroll
    for (int r = 0; r < 4; ++r) {
      int m = wm * 64 + mt * 16 + hi2 * 4 + r;
      int jr = i - K_WIN + m, jc = jr < 0 ? 0 : jr;
      const float* Vj = V + jc * H_PAD;
      #pragma unroll
      for (int nt = 0; nt < 5; ++nt) {
        int h = wn * 80 + nt * 16 + lo4;
        float val = acc[mt][nt][r] + Vj[h];
        val = (h < H_DIM) ? fmaxf(val, 0.f) : 0.f;
        int tile = h >> 6, hc = h & 63;
        int byte = tile * 16384 + m * 128 + ((hc * 2) ^ ((m & 7) << 4));
        *((short*)(Hb + byte)) = f2bf_hw(val);
      }
    }
  }
  // zero tile2 bytes 64..127 (XOR addressing touches them for k=128..159 reads)
  {
    short8 z = {0, 0, 0, 0, 0, 0, 0, 0};
    for (int c = tid; c < 512; c += 256) {
      int row = c >> 2, cb = c & 3;
      int byte = 2 * 16384 + row * 128 + ((64 + cb * 16) ^ ((row & 7) << 4));
      *((short8*)(Hb + byte)) = z;
    }
  }
  __syncthreads();

  // ---- layer 2: D2 = h1 @ W2 (K=160), B direct from global (L2), reg dbuf ----
  float4_t acc2[4][5];
  #pragma unroll
  for (int a = 0; a < 4; ++a)
    #pragma unroll
    for (int b = 0; b < 5; ++b) acc2[a][b] = fz;

  short8 bql[2][5];
  #pragma unroll
  for (int nt = 0; nt < 5; ++nt) {
    int row = wn * 80 + nt * 16 + lo4;
    bql[0][nt] = *(const short8*)(W2T + row * H_PAD + hi2 * 8);
  }
  #pragma unroll
  for (int ks = 0; ks < 5; ++ks) {
    const int cur = ks & 1;
    if (ks < 4) {
      #pragma unroll
      for (int nt = 0; nt < 5; ++nt) {
        int row = wn * 80 + nt * 16 + lo4;
        bql[cur ^ 1][nt] = *(const short8*)(W2T + row * H_PAD + (ks + 1) * 32 + hi2 * 8);
      }
    }
    short8 af[4];
    #pragma unroll
    for (int mt = 0; mt < 4; ++mt) {
      int row = wm * 64 + mt * 16 + lo4;
      int kb = (ks & 1) * 64 + hi2 * 16;
      af[mt] = *((const short8*)(Hb + (ks >> 1) * 16384 + row * 128 + (kb ^ ((row & 7) << 4))));
    }
    #pragma unroll
    for (int mt = 0; mt < 4; ++mt)
      #pragma unroll
      for (int nt = 0; nt < 5; ++nt)
        acc2[mt][nt] = __builtin_amdgcn_mfma_f32_16x16x32_bf16(af[mt], bql[cur][nt], acc2[mt][nt], 0, 0, 0);
  }

  // ---- epilogue 2: s = relu(acc2 + b2) @ W3, reduce, emit ----
  float sp[4][4];
  #pragma unroll
  for (int mt = 0; mt < 4; ++mt)
    #pragma unroll
    for (int r = 0; r < 4; ++r) sp[mt][r] = 0.f;

  #pragma unroll
  for (int nt = 0; nt < 5; ++nt) {
    int h = wn * 80 + nt * 16 + lo4;
    float w3 = (h < H_DIM) ? W3[h] : 0.f;
    float bb = (h < H_DIM) ? b2[h] : 0.f;
    #pragma unroll
    for (int mt = 0; mt < 4; ++mt)
      #pragma unroll
      for (int r = 0; r < 4; ++r) {
        float hv = fmaxf(acc2[mt][nt][r] + bb, 0.f);
        sp[mt][r] += hv * w3;
      }
  }
  #pragma unroll
  for (int mt = 0; mt < 4; ++mt)
    #pragma unroll
    for (int r = 0; r < 4; ++r) {
      float v = sp[mt][r];
      v += __shfl_xor(v, 1);
      v += __shfl_xor(v, 2);
      v += __shfl_xor(v, 4);
      v += __shfl_xor(v, 8);
      sp[mt][r] = v;
    }
  if (lo4 == 0) {
    #pragma unroll
    for (int mt = 0; mt < 4; ++mt)
      #pragma unroll
      for (int r = 0; r < 4; ++r) {
        int m = wm * 64 + mt * 16 + hi2 * 4 + r;
        s_buf[wn][m] = sp[mt][r];
      }
  }
  __syncthreads();

  if (tid < K_WIN) {
    int m = tid;
    int jr = i - K_WIN + m;
    float sij = si[i] + sj_s[m] + s_buf[0][m] + s_buf[1][m] + b3[0];
    out[i * OUT_C + m] = (jr >= 0) ? sij : 0.f;
  }
  if (tid == K_WIN) out[i * OUT_C + K_WIN] = 0.f;
}

// ---------------------------------------------------------------------------
extern "C" void kernel_launch(void* const* d_in, const int* in_sizes, int n_in,
                              void* d_out, int out_size, void* d_ws, size_t ws_size,
                              hipStream_t stream) {
  const float* g  = (const float*)d_in[0];
  const float* si = (const float*)d_in[1];
  const int*   i1 = (const int*)d_in[2];
  const int*   i2 = (const int*)d_in[3];
  const float* de = (const float*)d_in[4];
  const float* W1 = (const float*)d_in[5];
  const float* b1 = (const float*)d_in[6];
  const float* W2 = (const float*)d_in[7];
  const float* b2 = (const float*)d_in[8];
  const float* W3 = (const float*)d_in[9];
  const float* b3 = (const float*)d_in[10];
  float* out = (float*)d_out;

  char* ws = (char*)d_ws;
  short* g_bf   = (short*)(ws);                 // 1,310,720
  short* W1cT   = (short*)(ws + 1310720);       //   204,800
  short* W1abT  = (short*)(ws + 1515520);       //   409,600
  short* W2T    = (short*)(ws + 1925120);       //    51,200
  short* deWT_g = (short*)(ws + 1976320);       //    20,480
  float* V      = (float*)(ws + 1996800);       //   655,360
  short* U_bf   = (short*)(ws + 2652160);       //   327,680  (total ~2.98 MB)

  prep_pack<<<321, 256, 0, stream>>>(g, W1, W2, de, g_bf, W1cT, W1abT, W2T, deWT_g);
  prep_uv_mfma<<<dim3(16, 2), 256, 0, stream>>>(g_bf, W1abT, b1, U_bf, V);
  pair_main<<<N_PTS, 256, 0, stream>>>(g, g_bf, W1cT, W2T, U_bf, V, deWT_g,
                                       si, i1, i2, W3, b2, b3, out);
}

// Round 6
// 88.951 us; speedup vs baseline: 2.5090x; 1.2231x over previous
//
#include <hip/hip_runtime.h>
#include <hip/hip_bf16.h>
#include <stdint.h>

typedef __attribute__((ext_vector_type(8))) short short8;
typedef __attribute__((ext_vector_type(4))) float float4_t;

#define N_PTS 1024
#define G_DIM 620
#define G_PAD 640
#define F_DIM 20
#define H_DIM 150
#define H_PAD 160
#define K_WIN 128
#define OUT_C (K_WIN + 1)

__device__ __forceinline__ float bf2f(short u) {
  union { unsigned int i; float f; } x;
  x.i = ((unsigned int)(unsigned short)u) << 16;
  return x.f;
}
__device__ __forceinline__ short f2bf(float f) {
  union { float f; unsigned int i; } x; x.f = f;
  unsigned int u = x.i;
  u += 0x7FFFu + ((u >> 16) & 1u);   // RNE
  return (short)(u >> 16);
}
__device__ __forceinline__ short f2bf_hw(float f) {
  __hip_bfloat16 h = __float2bfloat16(f);
  union { __hip_bfloat16 h; short s; } u; u.h = h;
  return u.s;
}
__device__ __forceinline__ void gload_lds16(const void* g, void* l) {
  __builtin_amdgcn_global_load_lds(
      (const __attribute__((address_space(1))) unsigned int*)g,
      (__attribute__((address_space(3))) unsigned int*)l, 16, 0, 0);
}

// ---------------------------------------------------------------------------
// prep_pack: grid 321 x 256.
//  [0,256)   : g_bf [1024][640] bf16
//  [256,316) : LDS-tiled transposes: thirds 0/1 -> W1abT, third 2 -> W1cT
//  [316,320) : W2T [160][160]
//  [320]     : deW f32 [9][160] = dist_emb @ W1d
// ---------------------------------------------------------------------------
__global__ void prep_pack(const float* __restrict__ g, const float* __restrict__ W1,
                          const float* __restrict__ W2, const float* __restrict__ dist_emb,
                          short* __restrict__ g_bf, short* __restrict__ W1cT,
                          short* __restrict__ W1abT, short* __restrict__ W2T,
                          float* __restrict__ deW) {
  __shared__ float lds[32 * 165];
  const int bx = blockIdx.x, tid = threadIdx.x;
  if (bx < 256) {
    const int n0 = bx * 4;
    for (int c = tid; c < 320; c += 256) {
      int r = c / 80, cc = c - r * 80;
      int n = n0 + r, d0 = cc * 8;
      short8 o;
      if (d0 + 8 <= G_DIM) {
        const float* src = g + n * G_DIM + d0;
        #pragma unroll
        for (int e = 0; e < 8; ++e) o[e] = f2bf(src[e]);
      } else {
        #pragma unroll
        for (int e = 0; e < 8; ++e) {
          int d = d0 + e;
          o[e] = (d < G_DIM) ? f2bf(g[n * G_DIM + d]) : (short)0;
        }
      }
      *(short8*)(g_bf + n * G_PAD + d0) = o;
    }
  } else if (bx < 316) {
    const int tb = bx - 256;
    const int third = tb / 20, dt = tb - third * 20;
    const int d0 = dt * 32;
    for (int c = tid; c < 1280; c += 256) {       // 32 d-rows x 40 chunks(4h)
      int dr = c / 40, ch4 = c - dr * 40;
      int dd = d0 + dr;
      int w1r = third * G_DIM + dd;
      #pragma unroll
      for (int e = 0; e < 4; ++e) {
        int h = ch4 * 4 + e;
        lds[dr * 165 + h] = (dd < G_DIM && h < H_DIM) ? W1[w1r * H_DIM + h] : 0.f;
      }
    }
    __syncthreads();
    short* outp = (third == 2) ? W1cT : (W1abT + third * H_PAD * G_PAD);
    for (int c = tid; c < 640; c += 256) {        // 160 h-rows x 4 chunks(8d)
      int h = c >> 2, ch = c & 3;
      short8 o;
      #pragma unroll
      for (int e = 0; e < 8; ++e) o[e] = f2bf(lds[(ch * 8 + e) * 165 + h]);
      *(short8*)(outp + h * G_PAD + d0 + ch * 8) = o;
    }
  } else if (bx < 320) {
    const int base = (bx - 316) * 6400;
    for (int c = tid; c < 6400; c += 256) {
      int q = base + c;
      int m = q / H_PAD, k = q - m * H_PAD;
      W2T[q] = (m < H_DIM && k < H_DIM) ? f2bf(W2[k * H_DIM + m]) : (short)0;
    }
  } else {
    for (int c = tid; c < 9 * H_PAD; c += 256) {
      int b = c / H_PAD, h = c - b * H_PAD;
      float acc = 0.f;
      if (h < H_DIM)
        for (int f = 0; f < F_DIM; ++f)
          acc += dist_emb[b * F_DIM + f] * W1[(3 * G_DIM + f) * H_DIM + h];
      deW[c] = acc;
    }
  }
}

// ---------------------------------------------------------------------------
// prep_uv_mfma: y=0 -> U (f32, +b1) ; y=1 -> V (f32). 32 rows/block, grid 32x2.
// ---------------------------------------------------------------------------
__global__ __launch_bounds__(256) void prep_uv_mfma(
    const short* __restrict__ g_bf, const short* __restrict__ W1abT,
    const float* __restrict__ b1, float* __restrict__ U, float* __restrict__ V) {
  __shared__ __align__(16) char sA[32 * 128];
  __shared__ __align__(16) char sB[160 * 128];
  const int m0 = blockIdx.x * 32;
  const int yb = blockIdx.y * H_PAD;
  const int tid = threadIdx.x, lane = tid & 63, wid = tid >> 6;
  const int wm = wid >> 1, wn = wid & 1;
  const int lo4 = lane & 15, hi2 = lane >> 4;
  const int l8 = lane >> 3, c8 = lane & 7;
  const int xe = (c8 ^ (l8 & 7)) * 8;

  const float4_t fz = {0.f, 0.f, 0.f, 0.f};
  float4_t acc[5];
  #pragma unroll
  for (int b = 0; b < 5; ++b) acc[b] = fz;

  for (int step = 0; step < 10; ++step) {
    const int d0 = step * 64;
    {
      int row = wid * 8 + l8;            // 32 rows
      gload_lds16(g_bf + (m0 + row) * G_PAD + d0 + xe, sA + (wid * 8) * 128);
    }
    #pragma unroll
    for (int cc = 0; cc < 5; ++cc) {
      int row = wid * 8 + cc * 32 + l8;
      gload_lds16(W1abT + (yb + row) * G_PAD + d0 + xe, sB + (wid * 8 + cc * 32) * 128);
    }
    __syncthreads();
    #pragma unroll
    for (int ks = 0; ks < 2; ++ks) {
      const int kb = ks * 64 + 16 * hi2;
      short8 af, bq[5];
      {
        int row = wm * 16 + lo4;
        af = *((const short8*)(sA + row * 128 + (kb ^ ((row & 7) << 4))));
      }
      #pragma unroll
      for (int nt = 0; nt < 5; ++nt) {
        int row = wn * 80 + nt * 16 + lo4;
        bq[nt] = *((const short8*)(sB + row * 128 + (kb ^ ((row & 7) << 4))));
      }
      #pragma unroll
      for (int nt = 0; nt < 5; ++nt)
        acc[nt] = __builtin_amdgcn_mfma_f32_16x16x32_bf16(af, bq[nt], acc[nt], 0, 0, 0);
    }
    __syncthreads();
  }

  const bool isU = (blockIdx.y == 0);
  float* O = isU ? U : V;
  #pragma unroll
  for (int r = 0; r < 4; ++r) {
    int m = m0 + wm * 16 + hi2 * 4 + r;
    #pragma unroll
    for (int nt = 0; nt < 5; ++nt) {
      int h = wn * 80 + nt * 16 + lo4;
      float v = acc[nt][r];
      if (h < H_DIM) { if (isU) v += b1[h]; } else { v = 0.f; }
      O[m * H_PAD + h] = v;
    }
  }
}

// ---------------------------------------------------------------------------
// pair_main: one block per i (XCD swizzle). 4 waves (2M x 2N), 2 blocks/CU.
// Layer1: B' = g_i-scaled W1c built in LDS (write-late, off critical path);
//         A = RAW g_bf fragments, register-prefetched one step ahead (no VALU).
//         10 steps BK=64, 1 barrier/step, every load issued a step early.
// Epi1:   h1 = relu(acc + U[i] + V[j] + deW[bin]) -> Hb swizzled bf16.
// Layer2: h1 @ W2T (direct global, reg dbuf). Epi2: @W3 reduce, emit.
// ---------------------------------------------------------------------------
__global__ __launch_bounds__(256, 2) void pair_main(
    const float* __restrict__ g, const short* __restrict__ g_bf,
    const short* __restrict__ W1cT, const short* __restrict__ W2T,
    const float* __restrict__ U, const float* __restrict__ V,
    const float* __restrict__ deW, const float* __restrict__ si,
    const int* __restrict__ i1, const int* __restrict__ i2,
    const float* __restrict__ W3, const float* __restrict__ b2,
    const float* __restrict__ b3, float* __restrict__ out) {
  __shared__ __align__(16) char smem[49152];     // B0|B1 (2x20480) / Hb (3x16384)
  __shared__ __align__(16) float gi_sf[G_PAD];
  __shared__ float sj_s[K_WIN];
  __shared__ unsigned char bin_su[K_WIN];
  __shared__ float s_buf[2][K_WIN];

  char* const B0 = smem;
  char* const B1 = smem + 20480;
  char* const Hb = smem;

  const int bid = blockIdx.x;
  const int i = ((bid & 7) << 7) | (bid >> 3);   // XCD-bijective swizzle
  const int tid = threadIdx.x;
  const int lane = tid & 63;
  const int wid = tid >> 6;
  const int wm = wid >> 1, wn = wid & 1;
  const int lo4 = lane & 15, hi2 = lane >> 4;

  // ---- preamble ----
  if (tid < 160) {
    float4_t v;
    if (tid < 155) v = *(const float4_t*)(g + i * G_DIM + tid * 4);
    else { v.x = v.y = v.z = v.w = 0.f; }
    *(float4_t*)(gi_sf + tid * 4) = v;
  }
  if (tid < K_WIN) {
    int jr = i - K_WIN + tid, jc = jr < 0 ? 0 : jr;
    int d = i2[i] - i1[jc];
    bin_su[tid] = (unsigned char)((d >= 1) + (d >= 2) + (d >= 3) + (d >= 4) +
                                  (d >= 8) + (d >= 16) + (d >= 32) + (d >= 64));
    sj_s[tid] = si[jc];
  }
  __syncthreads();

  // per-lane raw-A source pointers
  const short* gA[4];
  #pragma unroll
  for (int mt = 0; mt < 4; ++mt) {
    int row = wm * 64 + mt * 16 + lo4;
    int jr = i - K_WIN + row, jc = jr < 0 ? 0 : jr;
    gA[mt] = g_bf + jc * G_PAD + hi2 * 8;
  }
  // staging mapping: c = tid + 256*cc -> row = c>>3, chunk cb = c&7
  const int srow = tid >> 3;       // base row (cc adds 32 rows)
  const int scb = tid & 7;

  auto loadW1 = [&](int s, short8 (&w)[5]) {
    const short* base = W1cT + s * 64 + scb * 8;
    #pragma unroll
    for (int cc = 0; cc < 5; ++cc)
      w[cc] = *(const short8*)(base + (srow + cc * 32) * G_PAD);
  };
  auto loadGJ = [&](int s, short8 (&gj)[4][2]) {
    #pragma unroll
    for (int mt = 0; mt < 4; ++mt)
      #pragma unroll
      for (int ks = 0; ks < 2; ++ks)
        gj[mt][ks] = *(const short8*)(gA[mt] + s * 64 + ks * 32);
  };
  auto writeBp = [&](int s, const short8 (&w)[5], char* B) {
    const float* gp = gi_sf + s * 64 + scb * 8;
    float4_t g0 = *(const float4_t*)(gp);
    float4_t g1 = *(const float4_t*)(gp + 4);
    #pragma unroll
    for (int cc = 0; cc < 5; ++cc) {
      int row = srow + cc * 32;
      short8 o;
      #pragma unroll
      for (int e = 0; e < 4; ++e) {
        o[e]     = f2bf_hw(bf2f(w[cc][e])     * g0[e]);
        o[e + 4] = f2bf_hw(bf2f(w[cc][e + 4]) * g1[e]);
      }
      *(short8*)(B + row * 128 + ((scb * 16) ^ ((row & 7) << 4))) = o;
    }
  };

  const float4_t fz = {0.f, 0.f, 0.f, 0.f};
  float4_t acc[4][5];
  #pragma unroll
  for (int a = 0; a < 4; ++a)
    #pragma unroll
    for (int b = 0; b < 5; ++b) acc[a][b] = fz;

  auto mfma_step = [&](const short8 (&gj)[4][2], const char* Bc) {
    #pragma unroll
    for (int ks = 0; ks < 2; ++ks) {
      const int kb = ks * 64 + hi2 * 16;
      short8 bq[5];
      #pragma unroll
      for (int nt = 0; nt < 5; ++nt) {
        int row = wn * 80 + nt * 16 + lo4;
        bq[nt] = *((const short8*)(Bc + row * 128 + (kb ^ ((row & 7) << 4))));
      }
      #pragma unroll
      for (int mt = 0; mt < 4; ++mt)
        #pragma unroll
        for (int nt = 0; nt < 5; ++nt)
          acc[mt][nt] = __builtin_amdgcn_mfma_f32_16x16x32_bf16(gj[mt][ks], bq[nt], acc[mt][nt], 0, 0, 0);
    }
  };

  // ---- layer 1: 10 steps, software-pipelined (loads one step ahead) ----
  short8 wA[5], wB[5], gjA[4][2], gjB[4][2];
  loadW1(0, wA); loadGJ(0, gjA);
  writeBp(0, wA, B0);
  for (int ss = 0; ss < 5; ++ss) {
    // even step s = 2ss (reads B0, gjA)
    __syncthreads();
    loadW1(2 * ss + 1, wB); loadGJ(2 * ss + 1, gjB);
    mfma_step(gjA, B0);
    writeBp(2 * ss + 1, wB, B1);
    // odd step s = 2ss+1 (reads B1, gjB)
    __syncthreads();
    if (ss < 4) {
      loadW1(2 * ss + 2, wA); loadGJ(2 * ss + 2, gjA);
      mfma_step(gjB, B1);
      writeBp(2 * ss + 2, wA, B0);
    } else {
      mfma_step(gjB, B1);
    }
  }
  __syncthreads();   // layer-1 reads done; Hb may overwrite B0/B1

  // ---- epilogue 1: h1 = relu(acc + U[i] + V[j] + deW[bin]) -> Hb swz ----
  float uih[5];
  #pragma unroll
  for (int nt = 0; nt < 5; ++nt) uih[nt] = U[i * H_PAD + wn * 80 + nt * 16 + lo4];
  #pragma unroll
  for (int mt = 0; mt < 4; ++mt) {
    #pragma unroll
    for (int r = 0; r < 4; ++r) {
      int m = wm * 64 + mt * 16 + hi2 * 4 + r;
      int jr = i - K_WIN + m, jc = jr < 0 ? 0 : jr;
      const float* Vj = V + jc * H_PAD;
      const float* De = deW + bin_su[m] * H_PAD;
      #pragma unroll
      for (int nt = 0; nt < 5; ++nt) {
        int h = wn * 80 + nt * 16 + lo4;
        float val = acc[mt][nt][r] + uih[nt] + Vj[h] + De[h];
        val = (h < H_DIM) ? fmaxf(val, 0.f) : 0.f;
        int tile = h >> 6, hc = h & 63;
        int byte = tile * 16384 + m * 128 + ((hc * 2) ^ ((m & 7) << 4));
        *((short*)(Hb + byte)) = f2bf_hw(val);
      }
    }
  }
  // zero tile2 bytes 64..127 (XOR addressing touches them for k=128..159 reads)
  {
    short8 z = {0, 0, 0, 0, 0, 0, 0, 0};
    for (int c = tid; c < 512; c += 256) {
      int row = c >> 2, cb = c & 3;
      int byte = 2 * 16384 + row * 128 + ((64 + cb * 16) ^ ((row & 7) << 4));
      *((short8*)(Hb + byte)) = z;
    }
  }
  __syncthreads();

  // ---- layer 2: D2 = h1 @ W2 (K=160), B direct from global (L2), reg dbuf ----
  float4_t acc2[4][5];
  #pragma unroll
  for (int a = 0; a < 4; ++a)
    #pragma unroll
    for (int b = 0; b < 5; ++b) acc2[a][b] = fz;

  short8 bql[2][5];
  #pragma unroll
  for (int nt = 0; nt < 5; ++nt) {
    int row = wn * 80 + nt * 16 + lo4;
    bql[0][nt] = *(const short8*)(W2T + row * H_PAD + hi2 * 8);
  }
  #pragma unroll
  for (int ks = 0; ks < 5; ++ks) {
    const int cur = ks & 1;
    if (ks < 4) {
      #pragma unroll
      for (int nt = 0; nt < 5; ++nt) {
        int row = wn * 80 + nt * 16 + lo4;
        bql[cur ^ 1][nt] = *(const short8*)(W2T + row * H_PAD + (ks + 1) * 32 + hi2 * 8);
      }
    }
    short8 af[4];
    #pragma unroll
    for (int mt = 0; mt < 4; ++mt) {
      int row = wm * 64 + mt * 16 + lo4;
      int kb = (ks & 1) * 64 + hi2 * 16;
      af[mt] = *((const short8*)(Hb + (ks >> 1) * 16384 + row * 128 + (kb ^ ((row & 7) << 4))));
    }
    #pragma unroll
    for (int mt = 0; mt < 4; ++mt)
      #pragma unroll
      for (int nt = 0; nt < 5; ++nt)
        acc2[mt][nt] = __builtin_amdgcn_mfma_f32_16x16x32_bf16(af[mt], bql[cur][nt], acc2[mt][nt], 0, 0, 0);
  }

  // ---- epilogue 2: s = relu(acc2 + b2) @ W3, reduce, emit ----
  float sp[4][4];
  #pragma unroll
  for (int mt = 0; mt < 4; ++mt)
    #pragma unroll
    for (int r = 0; r < 4; ++r) sp[mt][r] = 0.f;

  #pragma unroll
  for (int nt = 0; nt < 5; ++nt) {
    int h = wn * 80 + nt * 16 + lo4;
    float w3 = (h < H_DIM) ? W3[h] : 0.f;
    float bb = (h < H_DIM) ? b2[h] : 0.f;
    #pragma unroll
    for (int mt = 0; mt < 4; ++mt)
      #pragma unroll
      for (int r = 0; r < 4; ++r) {
        float hv = fmaxf(acc2[mt][nt][r] + bb, 0.f);
        sp[mt][r] += hv * w3;
      }
  }
  #pragma unroll
  for (int mt = 0; mt < 4; ++mt)
    #pragma unroll
    for (int r = 0; r < 4; ++r) {
      float v = sp[mt][r];
      v += __shfl_xor(v, 1);
      v += __shfl_xor(v, 2);
      v += __shfl_xor(v, 4);
      v += __shfl_xor(v, 8);
      sp[mt][r] = v;
    }
  if (lo4 == 0) {
    #pragma unroll
    for (int mt = 0; mt < 4; ++mt)
      #pragma unroll
      for (int r = 0; r < 4; ++r) {
        int m = wm * 64 + mt * 16 + hi2 * 4 + r;
        s_buf[wn][m] = sp[mt][r];
      }
  }
  __syncthreads();

  if (tid < K_WIN) {
    int m = tid;
    int jr = i - K_WIN + m;
    float sij = si[i] + sj_s[m] + s_buf[0][m] + s_buf[1][m] + b3[0];
    out[i * OUT_C + m] = (jr >= 0) ? sij : 0.f;
  }
  if (tid == K_WIN) out[i * OUT_C + K_WIN] = 0.f;
}

// ---------------------------------------------------------------------------
extern "C" void kernel_launch(void* const* d_in, const int* in_sizes, int n_in,
                              void* d_out, int out_size, void* d_ws, size_t ws_size,
                              hipStream_t stream) {
  const float* g  = (const float*)d_in[0];
  const float* si = (const float*)d_in[1];
  const int*   i1 = (const int*)d_in[2];
  const int*   i2 = (const int*)d_in[3];
  const float* de = (const float*)d_in[4];
  const float* W1 = (const float*)d_in[5];
  const float* b1 = (const float*)d_in[6];
  const float* W2 = (const float*)d_in[7];
  const float* b2 = (const float*)d_in[8];
  const float* W3 = (const float*)d_in[9];
  const float* b3 = (const float*)d_in[10];
  float* out = (float*)d_out;

  char* ws = (char*)d_ws;
  short* g_bf  = (short*)(ws);                 // 1,310,720
  short* W1cT  = (short*)(ws + 1310720);       //   204,800
  short* W1abT = (short*)(ws + 1515520);       //   409,600
  short* W2T   = (short*)(ws + 1925120);       //    51,200
  float* U     = (float*)(ws + 1976320);       //   655,360
  float* V     = (float*)(ws + 2631680);       //   655,360
  float* deW   = (float*)(ws + 3287040);       //     5,760  (total ~3.29 MB)

  prep_pack<<<321, 256, 0, stream>>>(g, W1, W2, de, g_bf, W1cT, W1abT, W2T, deW);
  prep_uv_mfma<<<dim3(32, 2), 256, 0, stream>>>(g_bf, W1abT, b1, U, V);
  pair_main<<<N_PTS, 256, 0, stream>>>(g, g_bf, W1cT, W2T, U, V, deW,
                                       si, i1, i2, W3, b2, b3, out);
}

// Round 7
// 71.830 us; speedup vs baseline: 3.1070x; 1.2384x over previous
//
#include <hip/hip_runtime.h>
#include <hip/hip_bf16.h>
#include <stdint.h>

typedef __attribute__((ext_vector_type(8))) short short8;
typedef __attribute__((ext_vector_type(4))) float float4_t;

#define N_PTS 1024
#define G_DIM 620
#define G_PAD 640
#define F_DIM 20
#define H_DIM 150
#define H_PAD 160
#define K_WIN 128
#define OUT_C (K_WIN + 1)

__device__ __forceinline__ float bf2f(short u) {
  union { unsigned int i; float f; } x;
  x.i = ((unsigned int)(unsigned short)u) << 16;
  return x.f;
}
__device__ __forceinline__ short f2bf(float f) {
  union { float f; unsigned int i; } x; x.f = f;
  unsigned int u = x.i;
  u += 0x7FFFu + ((u >> 16) & 1u);   // RNE
  return (short)(u >> 16);
}
__device__ __forceinline__ short f2bf_hw(float f) {
  __hip_bfloat16 h = __float2bfloat16(f);
  union { __hip_bfloat16 h; short s; } u; u.h = h;
  return u.s;
}
__device__ __forceinline__ void gload_lds16(const void* g, void* l) {
  __builtin_amdgcn_global_load_lds(
      (const __attribute__((address_space(1))) unsigned int*)g,
      (__attribute__((address_space(3))) unsigned int*)l, 16, 0, 0);
}

// ---------------------------------------------------------------------------
// prep_pack: grid 321 x 256 (r6 version — measured fast).
//  [0,256)   : g_bf [1024][640] bf16
//  [256,316) : LDS-tiled transposes: thirds 0/1 -> W1abT, third 2 -> W1cT
//  [316,320) : W2T [160][160]
//  [320]     : deW f32 [9][160] = dist_emb @ W1d
// ---------------------------------------------------------------------------
__global__ void prep_pack(const float* __restrict__ g, const float* __restrict__ W1,
                          const float* __restrict__ W2, const float* __restrict__ dist_emb,
                          short* __restrict__ g_bf, short* __restrict__ W1cT,
                          short* __restrict__ W1abT, short* __restrict__ W2T,
                          float* __restrict__ deW) {
  __shared__ float lds[32 * 165];
  const int bx = blockIdx.x, tid = threadIdx.x;
  if (bx < 256) {
    const int n0 = bx * 4;
    for (int c = tid; c < 320; c += 256) {
      int r = c / 80, cc = c - r * 80;
      int n = n0 + r, d0 = cc * 8;
      short8 o;
      if (d0 + 8 <= G_DIM) {
        const float* src = g + n * G_DIM + d0;
        #pragma unroll
        for (int e = 0; e < 8; ++e) o[e] = f2bf(src[e]);
      } else {
        #pragma unroll
        for (int e = 0; e < 8; ++e) {
          int d = d0 + e;
          o[e] = (d < G_DIM) ? f2bf(g[n * G_DIM + d]) : (short)0;
        }
      }
      *(short8*)(g_bf + n * G_PAD + d0) = o;
    }
  } else if (bx < 316) {
    const int tb = bx - 256;
    const int third = tb / 20, dt = tb - third * 20;
    const int d0 = dt * 32;
    for (int c = tid; c < 1280; c += 256) {       // 32 d-rows x 40 chunks(4h)
      int dr = c / 40, ch4 = c - dr * 40;
      int dd = d0 + dr;
      int w1r = third * G_DIM + dd;
      #pragma unroll
      for (int e = 0; e < 4; ++e) {
        int h = ch4 * 4 + e;
        lds[dr * 165 + h] = (dd < G_DIM && h < H_DIM) ? W1[w1r * H_DIM + h] : 0.f;
      }
    }
    __syncthreads();
    short* outp = (third == 2) ? W1cT : (W1abT + third * H_PAD * G_PAD);
    for (int c = tid; c < 640; c += 256) {        // 160 h-rows x 4 chunks(8d)
      int h = c >> 2, ch = c & 3;
      short8 o;
      #pragma unroll
      for (int e = 0; e < 8; ++e) o[e] = f2bf(lds[(ch * 8 + e) * 165 + h]);
      *(short8*)(outp + h * G_PAD + d0 + ch * 8) = o;
    }
  } else if (bx < 320) {
    const int base = (bx - 316) * 6400;
    for (int c = tid; c < 6400; c += 256) {
      int q = base + c;
      int m = q / H_PAD, k = q - m * H_PAD;
      W2T[q] = (m < H_DIM && k < H_DIM) ? f2bf(W2[k * H_DIM + m]) : (short)0;
    }
  } else {
    for (int c = tid; c < 9 * H_PAD; c += 256) {
      int b = c / H_PAD, h = c - b * H_PAD;
      float acc = 0.f;
      if (h < H_DIM)
        for (int f = 0; f < F_DIM; ++f)
          acc += dist_emb[b * F_DIM + f] * W1[(3 * G_DIM + f) * H_DIM + h];
      deW[c] = acc;
    }
  }
}

// ---------------------------------------------------------------------------
// prep_uv_mfma: y=0 -> U (f32, +b1) ; y=1 -> V (f32). 32 rows/block, grid 32x2.
// ---------------------------------------------------------------------------
__global__ __launch_bounds__(256) void prep_uv_mfma(
    const short* __restrict__ g_bf, const short* __restrict__ W1abT,
    const float* __restrict__ b1, float* __restrict__ U, float* __restrict__ V) {
  __shared__ __align__(16) char sA[32 * 128];
  __shared__ __align__(16) char sB[160 * 128];
  const int m0 = blockIdx.x * 32;
  const int yb = blockIdx.y * H_PAD;
  const int tid = threadIdx.x, lane = tid & 63, wid = tid >> 6;
  const int wm = wid >> 1, wn = wid & 1;
  const int lo4 = lane & 15, hi2 = lane >> 4;
  const int l8 = lane >> 3, c8 = lane & 7;
  const int xe = (c8 ^ (l8 & 7)) * 8;

  const float4_t fz = {0.f, 0.f, 0.f, 0.f};
  float4_t acc[5];
  #pragma unroll
  for (int b = 0; b < 5; ++b) acc[b] = fz;

  for (int step = 0; step < 10; ++step) {
    const int d0 = step * 64;
    {
      int row = wid * 8 + l8;            // 32 rows
      gload_lds16(g_bf + (m0 + row) * G_PAD + d0 + xe, sA + (wid * 8) * 128);
    }
    #pragma unroll
    for (int cc = 0; cc < 5; ++cc) {
      int row = wid * 8 + cc * 32 + l8;
      gload_lds16(W1abT + (yb + row) * G_PAD + d0 + xe, sB + (wid * 8 + cc * 32) * 128);
    }
    __syncthreads();
    #pragma unroll
    for (int ks = 0; ks < 2; ++ks) {
      const int kb = ks * 64 + 16 * hi2;
      short8 af, bq[5];
      {
        int row = wm * 16 + lo4;
        af = *((const short8*)(sA + row * 128 + (kb ^ ((row & 7) << 4))));
      }
      #pragma unroll
      for (int nt = 0; nt < 5; ++nt) {
        int row = wn * 80 + nt * 16 + lo4;
        bq[nt] = *((const short8*)(sB + row * 128 + (kb ^ ((row & 7) << 4))));
      }
      #pragma unroll
      for (int nt = 0; nt < 5; ++nt)
        acc[nt] = __builtin_amdgcn_mfma_f32_16x16x32_bf16(af, bq[nt], acc[nt], 0, 0, 0);
    }
    __syncthreads();
  }

  const bool isU = (blockIdx.y == 0);
  float* O = isU ? U : V;
  #pragma unroll
  for (int r = 0; r < 4; ++r) {
    int m = m0 + wm * 16 + hi2 * 4 + r;
    #pragma unroll
    for (int nt = 0; nt < 5; ++nt) {
      int h = wn * 80 + nt * 16 + lo4;
      float v = acc[nt][r];
      if (h < H_DIM) { if (isU) v += b1[h]; } else { v = 0.f; }
      O[m * H_PAD + h] = v;
    }
  }
}

// ---------------------------------------------------------------------------
// pair_main (r2 structure revived): one block per i (XCD swizzle), 4 waves
// (2M x 2N), 2 blocks/CU. Layer1: P = gj.*gi staged coalesced->LDS (dbuf),
// B = W1cT via global_load_lds (dbuf), 1 barrier/step, gj issued BEFORE
// B-gloads so writeP waits vmcnt(5) not 0. Layer2: W2T direct-global reg-dbuf.
// ---------------------------------------------------------------------------
__global__ __launch_bounds__(256, 2) void pair_main(
    const short* __restrict__ g_bf, const short* __restrict__ W1cT,
    const short* __restrict__ W2T, const float* __restrict__ U,
    const float* __restrict__ V, const float* __restrict__ deW,
    const float* __restrict__ si, const int* __restrict__ i1,
    const int* __restrict__ i2, const float* __restrict__ W3,
    const float* __restrict__ b2, const float* __restrict__ b3,
    float* __restrict__ out) {
  __shared__ __align__(16) char smem[73728];     // P0|P1|B0|B1 / Hb union
  __shared__ __align__(16) short gi_s[G_PAD];
  __shared__ float sj_s[K_WIN];
  __shared__ unsigned char bin_su[K_WIN];
  __shared__ float s_buf[2][K_WIN];

  char* const P0 = smem;              // 16 KB
  char* const P1 = smem + 16384;      // 16 KB
  char* const B0 = smem + 32768;      // 20 KB
  char* const B1 = smem + 53248;      // 20 KB
  char* const Hb = smem;              // 3 x 16 KB (aliases P0,P1,B0 after L1)

  const int bid = blockIdx.x;
  const int i = ((bid & 7) << 7) | (bid >> 3);   // XCD-bijective swizzle
  const int tid = threadIdx.x;
  const int lane = tid & 63;
  const int wid = tid >> 6;
  const int wm = wid >> 1, wn = wid & 1;
  const int lo4 = lane & 15, hi2 = lane >> 4;
  const int l8 = lane >> 3, c8 = lane & 7;
  const int xe = (c8 ^ (l8 & 7)) * 8;            // pre-swizzled source chunk
  const int tc8 = tid & 7;

  // ---- preamble ----
  if (tid < G_PAD / 8)
    ((short8*)gi_s)[tid] = ((const short8*)(g_bf + i * G_PAD))[tid];
  if (tid < K_WIN) {
    int jr = i - K_WIN + tid, jc = jr < 0 ? 0 : jr;
    int d = i2[i] - i1[jc];
    bin_su[tid] = (unsigned char)((d >= 1) + (d >= 2) + (d >= 3) + (d >= 4) +
                                  (d >= 8) + (d >= 16) + (d >= 32) + (d >= 64));
    sj_s[tid] = si[jc];
  }
  __syncthreads();

  // ---- staging helpers ----
  auto loadA = [&](int s, short8 (&gjv)[4], short8& gvv) {
    const int d0 = s * 64;
    gvv = *((const short8*)(gi_s + d0 + tc8 * 8));
    #pragma unroll
    for (int cc = 0; cc < 4; ++cc) {
      int c = tid + 256 * cc, row = c >> 3;
      int jr = i - K_WIN + row, jc = jr < 0 ? 0 : jr;
      gjv[cc] = *((const short8*)(g_bf + jc * G_PAD + d0 + tc8 * 8));
    }
  };
  auto stageB = [&](int s, char* B) {   // W1cT K-slice -> LDS direct (async)
    const int d0 = s * 64;
    #pragma unroll
    for (int cc = 0; cc < 5; ++cc) {
      int row = wid * 8 + cc * 32 + l8;
      gload_lds16(W1cT + row * G_PAD + d0 + xe, B + (wid * 8 + cc * 32) * 128);
    }
  };
  auto writeP = [&](char* P, const short8 (&gjv)[4], const short8& gvv) {
    #pragma unroll
    for (int cc = 0; cc < 4; ++cc) {
      int c = tid + 256 * cc, row = c >> 3;
      short8 p;
      #pragma unroll
      for (int e = 0; e < 8; ++e) p[e] = f2bf_hw(bf2f(gjv[cc][e]) * bf2f(gvv[e]));
      int byte = row * 128 + ((tc8 * 16) ^ ((row & 7) << 4));
      *((short8*)(P + byte)) = p;
    }
  };

  // ---- prologue: stage step 0 (gj first, then async B) ----
  {
    short8 gjv[4], gvv;
    loadA(0, gjv, gvv);
    stageB(0, B0);
    writeP(P0, gjv, gvv);
  }

  const float4_t fz = {0.f, 0.f, 0.f, 0.f};
  float4_t acc[4][5];
  #pragma unroll
  for (int a = 0; a < 4; ++a)
    #pragma unroll
    for (int b = 0; b < 5; ++b) acc[a][b] = fz;

  // ---- layer 1: 10 K-steps, one barrier per step, dbuf ----
  for (int s = 0; s < 10; ++s) {
    char* Pc = (s & 1) ? P1 : P0;
    char* Bc = (s & 1) ? B1 : B0;
    char* Pn = (s & 1) ? P0 : P1;
    char* Bn = (s & 1) ? B0 : B1;
    __syncthreads();                    // buf[cur] staged, buf[next] free
    short8 gjv[4], gvv;
    if (s < 9) {
      loadA(s + 1, gjv, gvv);           // gj regs FIRST (writeP -> vmcnt(5))
      stageB(s + 1, Bn);                // async LDS-direct, in flight over MFMA
    }
    __builtin_amdgcn_s_setprio(1);
    #pragma unroll
    for (int ks = 0; ks < 2; ++ks) {
      const int kb = ks * 64 + 16 * hi2;
      short8 af[4], bq[5];
      #pragma unroll
      for (int mt = 0; mt < 4; ++mt) {
        int row = wm * 64 + mt * 16 + lo4;
        af[mt] = *((const short8*)(Pc + row * 128 + (kb ^ ((row & 7) << 4))));
      }
      #pragma unroll
      for (int nt = 0; nt < 5; ++nt) {
        int row = wn * 80 + nt * 16 + lo4;
        bq[nt] = *((const short8*)(Bc + row * 128 + (kb ^ ((row & 7) << 4))));
      }
      #pragma unroll
      for (int mt = 0; mt < 4; ++mt)
        #pragma unroll
        for (int nt = 0; nt < 5; ++nt)
          acc[mt][nt] = __builtin_amdgcn_mfma_f32_16x16x32_bf16(af[mt], bq[nt], acc[mt][nt], 0, 0, 0);
    }
    __builtin_amdgcn_s_setprio(0);
    if (s < 9) writeP(Pn, gjv, gvv);    // convert + write-late
  }
  __syncthreads();  // all layer-1 reads done before Hb overwrites P0/P1/B0

  // ---- epilogue 1: h1 = relu(acc + U[i] + V[j] + deW[bin]) -> Hb bf16 swz ----
  float uih[5];
  #pragma unroll
  for (int nt = 0; nt < 5; ++nt) uih[nt] = U[i * H_PAD + wn * 80 + nt * 16 + lo4];
  #pragma unroll
  for (int mt = 0; mt < 4; ++mt) {
    #pragma unroll
    for (int r = 0; r < 4; ++r) {
      int m = wm * 64 + mt * 16 + hi2 * 4 + r;
      int jr = i - K_WIN + m, jc = jr < 0 ? 0 : jr;
      const float* Vj = V + jc * H_PAD;
      const float* De = deW + bin_su[m] * H_PAD;
      #pragma unroll
      for (int nt = 0; nt < 5; ++nt) {
        int h = wn * 80 + nt * 16 + lo4;
        float val = acc[mt][nt][r] + uih[nt] + Vj[h] + De[h];
        val = (h < H_DIM) ? fmaxf(val, 0.f) : 0.f;
        int tile = h >> 6, hc = h & 63;
        int byte = tile * 16384 + m * 128 + ((hc * 2) ^ ((m & 7) << 4));
        *((short*)(Hb + byte)) = f2bf_hw(val);
      }
    }
  }
  // zero tile2 bytes 64..127 (XOR addressing touches them for k=128..159 reads)
  {
    short8 z = {0, 0, 0, 0, 0, 0, 0, 0};
    for (int c = tid; c < 512; c += 256) {
      int row = c >> 2, cb = c & 3;
      int byte = 2 * 16384 + row * 128 + ((64 + cb * 16) ^ ((row & 7) << 4));
      *((short8*)(Hb + byte)) = z;
    }
  }
  __syncthreads();

  // ---- layer 2: D2 = h1 @ W2 (K=160), B direct from global (L2), reg dbuf ----
  float4_t acc2[4][5];
  #pragma unroll
  for (int a = 0; a < 4; ++a)
    #pragma unroll
    for (int b = 0; b < 5; ++b) acc2[a][b] = fz;

  short8 bql[2][5];
  #pragma unroll
  for (int nt = 0; nt < 5; ++nt) {
    int row = wn * 80 + nt * 16 + lo4;
    bql[0][nt] = *(const short8*)(W2T + row * H_PAD + hi2 * 8);
  }
  #pragma unroll
  for (int ks = 0; ks < 5; ++ks) {
    const int cur = ks & 1;
    if (ks < 4) {
      #pragma unroll
      for (int nt = 0; nt < 5; ++nt) {
        int row = wn * 80 + nt * 16 + lo4;
        bql[cur ^ 1][nt] = *(const short8*)(W2T + row * H_PAD + (ks + 1) * 32 + hi2 * 8);
      }
    }
    short8 af[4];
    #pragma unroll
    for (int mt = 0; mt < 4; ++mt) {
      int row = wm * 64 + mt * 16 + lo4;
      int kb = (ks & 1) * 64 + hi2 * 16;
      af[mt] = *((const short8*)(Hb + (ks >> 1) * 16384 + row * 128 + (kb ^ ((row & 7) << 4))));
    }
    __builtin_amdgcn_s_setprio(1);
    #pragma unroll
    for (int mt = 0; mt < 4; ++mt)
      #pragma unroll
      for (int nt = 0; nt < 5; ++nt)
        acc2[mt][nt] = __builtin_amdgcn_mfma_f32_16x16x32_bf16(af[mt], bql[cur][nt], acc2[mt][nt], 0, 0, 0);
    __builtin_amdgcn_s_setprio(0);
  }

  // ---- epilogue 2: s = relu(acc2 + b2) @ W3, reduce, emit ----
  float sp[4][4];
  #pragma unroll
  for (int mt = 0; mt < 4; ++mt)
    #pragma unroll
    for (int r = 0; r < 4; ++r) sp[mt][r] = 0.f;

  #pragma unroll
  for (int nt = 0; nt < 5; ++nt) {
    int h = wn * 80 + nt * 16 + lo4;
    float w3 = (h < H_DIM) ? W3[h] : 0.f;
    float bb = (h < H_DIM) ? b2[h] : 0.f;
    #pragma unroll
    for (int mt = 0; mt < 4; ++mt)
      #pragma unroll
      for (int r = 0; r < 4; ++r) {
        float hv = fmaxf(acc2[mt][nt][r] + bb, 0.f);
        sp[mt][r] += hv * w3;
      }
  }
  #pragma unroll
  for (int mt = 0; mt < 4; ++mt)
    #pragma unroll
    for (int r = 0; r < 4; ++r) {
      float v = sp[mt][r];
      v += __shfl_xor(v, 1);
      v += __shfl_xor(v, 2);
      v += __shfl_xor(v, 4);
      v += __shfl_xor(v, 8);
      sp[mt][r] = v;
    }
  if (lo4 == 0) {
    #pragma unroll
    for (int mt = 0; mt < 4; ++mt)
      #pragma unroll
      for (int r = 0; r < 4; ++r) {
        int m = wm * 64 + mt * 16 + hi2 * 4 + r;
        s_buf[wn][m] = sp[mt][r];
      }
  }
  __syncthreads();

  if (tid < K_WIN) {
    int m = tid;
    int jr = i - K_WIN + m;
    float sij = si[i] + sj_s[m] + s_buf[0][m] + s_buf[1][m] + b3[0];
    out[i * OUT_C + m] = (jr >= 0) ? sij : 0.f;
  }
  if (tid == K_WIN) out[i * OUT_C + K_WIN] = 0.f;
}

// ---------------------------------------------------------------------------
extern "C" void kernel_launch(void* const* d_in, const int* in_sizes, int n_in,
                              void* d_out, int out_size, void* d_ws, size_t ws_size,
                              hipStream_t stream) {
  const float* g  = (const float*)d_in[0];
  const float* si = (const float*)d_in[1];
  const int*   i1 = (const int*)d_in[2];
  const int*   i2 = (const int*)d_in[3];
  const float* de = (const float*)d_in[4];
  const float* W1 = (const float*)d_in[5];
  const float* b1 = (const float*)d_in[6];
  const float* W2 = (const float*)d_in[7];
  const float* b2 = (const float*)d_in[8];
  const float* W3 = (const float*)d_in[9];
  const float* b3 = (const float*)d_in[10];
  float* out = (float*)d_out;

  char* ws = (char*)d_ws;
  short* g_bf  = (short*)(ws);                 // 1,310,720
  short* W1cT  = (short*)(ws + 1310720);       //   204,800
  short* W1abT = (short*)(ws + 1515520);       //   409,600
  short* W2T   = (short*)(ws + 1925120);       //    51,200
  float* U     = (float*)(ws + 1976320);       //   655,360
  float* V     = (float*)(ws + 2631680);       //   655,360
  float* deW   = (float*)(ws + 3287040);       //     5,760  (total ~3.29 MB)

  prep_pack<<<321, 256, 0, stream>>>(g, W1, W2, de, g_bf, W1cT, W1abT, W2T, deW);
  prep_uv_mfma<<<dim3(32, 2), 256, 0, stream>>>(g_bf, W1abT, b1, U, V);
  pair_main<<<N_PTS, 256, 0, stream>>>(g_bf, W1cT, W2T, U, V, deW,
                                       si, i1, i2, W3, b2, b3, out);
}